// Round 5
// baseline (2064.899 us; speedup 1.0000x reference)
//
#include <hip/hip_runtime.h>

#define NN 1024
#define MM 1024
#define NB 16
#define BIGF 1.0e10f
#define NW 8                        // waves per workgroup
#define OFS 5                       // interval offset between adjacent waves
#define CW 16                       // steps (columns) per interval
#define NA 68                       // active intervals per wave (68*16 = 1088 steps)
#define NGI (OFS * (NW - 1) + NA)   // 103 global intervals

__device__ __forceinline__ float softmin3f(float a, float b, float c) {
  float mn = fminf(a, fminf(b, c));
  float s = __expf(mn - a) + __expf(mn - b) + __expf(mn - c);
  return mn - __logf(s);
}

// D[b,i,j] = (x[b,i] - y[j])^2 ; coalesced float4 writes
__global__ __launch_bounds__(256) void d_init_kernel(const float* __restrict__ x,
                                                     const float* __restrict__ y,
                                                     float* __restrict__ D) {
  size_t idx = ((size_t)blockIdx.x * blockDim.x + threadIdx.x) * 4;
  int j = (int)(idx & (MM - 1));
  size_t bi = idx >> 10;
  float xi = x[bi];
  const float4 yv = *reinterpret_cast<const float4*>(y + j);
  float t0 = xi - yv.x, t1 = xi - yv.y, t2 = xi - yv.z, t3 = xi - yv.w;
  float4 o;
  o.x = t0 * t0; o.y = t1 * t1; o.z = t2 * t2; o.w = t3 * t3;
  *reinterpret_cast<float4*>(D + idx) = o;
}

// R boundary: R[b,0,0]=0, R[b,0,j>=1]=BIG, R[b,i>=1,0]=BIG
__global__ __launch_bounds__(1024) void r_bound_kernel(float* __restrict__ R) {
  int b = blockIdx.x, t = threadIdx.x;
  float* Rb = R + (size_t)b * (NN + 1) * (MM + 1);
  Rb[t + 1] = BIGF;
  Rb[(size_t)(t + 1) * (MM + 1)] = BIGF;
  if (t == 0) Rb[0] = 0.0f;
}

// ---------------- forward ---------------------------------------------------
// Wave w owns rows 128w+1..128w+128; lane l owns i1=128w+2l+1, i2=i1+1.
// Lane l at step s computes col j = s - l (both rows). Up/diag neighbors come
// from __shfl_up of lane l-1's i2-history; strip boundary row comes from an
// LDS ring written by wave w-1 (which runs OFS intervals ahead).
// Output R staged per 16-step window in a per-wave parallelogram LDS tile
// (addr = 33*l + {0,16} + p : odd lane stride, conflict-free), then
// cooperatively stored coalesced (4 rows x 16 consecutive cols per inst).
__global__ __launch_bounds__(512) void sdtw_fwd(const float* __restrict__ x,
                                                const float* __restrict__ y,
                                                float* __restrict__ R,
                                                float* __restrict__ score) {
  __shared__ float ylds[MM];
  __shared__ float tile[NW][2112];
  __shared__ float ringR[NW][128];
  const int b = blockIdx.x, t = threadIdx.x;
  const int w = t >> 6, l = t & 63;
  float* __restrict__ Rb = R + (size_t)b * (NN + 1) * (MM + 1);
  for (int k = t; k < MM; k += 512) ylds[k] = y[k];
  const int i1 = 128 * w + 2 * l + 1;
  const float x1 = x[b * NN + i1 - 1];
  const float x2 = x[b * NN + i1];
  float* tl = &tile[w][33 * l];
  const int wm1 = (w > 0) ? (w - 1) : 0;
  const bool L0 = (l == 0), W0 = (w == 0);
  const bool pub = (l == 63) && (w < NW - 1);
  float c1 = BIGF, c2 = BIGF, m1 = BIGF, m2 = BIGF, ringPrev = BIGF;
  __syncthreads();
  for (int G = 0; G < NGI; ++G) {
    const int a = G - OFS * w;
    if (a >= 0 && a < NA) {
      const int s0 = a * CW;
#pragma unroll
      for (int p = 0; p < CW; ++p) {
        const int j = s0 + p - l;
        const bool act = (j >= 1) && (j <= MM);
        float up = __shfl_up(m1, 1);   // R(i1-1, j)
        float dg = __shfl_up(m2, 1);   // R(i1-1, j-1)
        const float rc = ringR[wm1][j & 127];
        if (L0) {
          up = W0 ? BIGF : rc;
          dg = W0 ? ((j == 1) ? 0.0f : BIGF) : ringPrev;
        }
        ringPrev = act ? rc : ringPrev;
        const float yv = ylds[act ? (j - 1) : 0];
        float dv1 = x1 - yv; dv1 *= dv1;
        const float r1 = dv1 + softmin3f(dg, up, c1);
        float dv2 = x2 - yv; dv2 *= dv2;
        const float r2 = dv2 + softmin3f(c1, r1, c2);
        tl[p] = r1;
        tl[16 + p] = r2;
        if (pub && act) ringR[w][j & 127] = r2;
        m2 = act ? m1 : m2;
        m1 = act ? r2 : m1;
        c1 = act ? r1 : c1;
        c2 = act ? r2 : c2;
      }
      __builtin_amdgcn_wave_barrier();
      // cooperative coalesced store of window a (own wave's tile only)
#pragma unroll
      for (int g = 0; g < 32; ++g) {
        const int rr = 4 * g + (l >> 4);
        const int sl = l & 15;
        const int col = s0 + sl - (rr >> 1);
        const float v = tile[w][rr * 16 + (rr >> 1) + sl];
        if (col >= 1 && col <= MM)
          Rb[(size_t)(128 * w + 1 + rr) * (MM + 1) + col] = v;
      }
    }
    __syncthreads();
  }
  if (w == NW - 1 && l == 63) score[b] = m1;  // R[1024][1024]
}

// ---------------- backward --------------------------------------------------
// Rbar(i,j) = seed + E(i+1,j)exp(R(i+1,j)-R(i,j)-D(i+1,j))
//                  + E(i,j+1)exp(R(i,j+1)-R(i,j)-D(i,j+1))
//                  + E(i+1,j+1)exp(R(i+1,j+1)-R(i,j)-D(i+1,j+1))
// Wave w owns strip q=7-w (bottom strip first); lane l owns i1=128q+2l+1,
// i2=i1+1; step s computes col j = 1087 - s - l (right-to-left; lane l+1
// leads). Down-neighbors via __shfl_down of lane l+1's i1 history; strip
// boundary (row 128q+129) via E/R LDS rings from wave w-1. R input is
// coop-loaded per window into the tile and overwritten in place with E.
__global__ __launch_bounds__(512) void sdtw_bwd(const float* __restrict__ x,
                                                const float* __restrict__ y,
                                                const float* __restrict__ R,
                                                float* __restrict__ E) {
  __shared__ float ylds[MM];
  __shared__ float tile[NW][2112];
  __shared__ float ringEl[NW][128];
  __shared__ float ringRl[NW][128];
  const int b = blockIdx.x, t = threadIdx.x;
  const int w = t >> 6, l = t & 63;
  const int q = NW - 1 - w;  // strip (rows 128q+1 .. 128q+128)
  const float* __restrict__ Rb = R + (size_t)b * (NN + 1) * (MM + 1);
  float* __restrict__ Eb = E + (size_t)b * (size_t)NN * MM;
  for (int k = t; k < MM; k += 512) ylds[k] = y[k];
  const int i1 = 128 * q + 2 * l + 1, i2 = i1 + 1;
  const float xa = x[b * NN + i1 - 1];                       // x(i1)
  const float xb = x[b * NN + i1];                           // x(i2) = x(i1+1)
  const float xc = x[b * NN + ((i2 < NN) ? i2 : (NN - 1))];  // x(i2+1), clamped
  const bool vdn2 = (i2 < NN);
  const bool seedL = (i2 == NN);  // only wave 0 lane 63
  float* tl = &tile[w][33 * l];
  const int wm1 = (w > 0) ? (w - 1) : 0;
  const bool L63 = (l == 63);
  const bool pub = (l == 0) && (w < NW - 1);
  float a1e = 0.f, a1r = -BIGF, a2e = 0.f, a2r = -BIGF;  // own i1 history
  float b1e = 0.f, b1r = -BIGF;                          // own i2 history
  float rpE = 0.f, rpR = -BIGF;                          // ring rotate (j+1)
  float yj = 0.f;
  // prologue: coop-load R window a=0 into tile
#pragma unroll
  for (int g = 0; g < 32; ++g) {
    const int rr = 4 * g + (l >> 4);
    const int sl = l & 15;
    const int col = 1087 - sl - (rr >> 1);
    tile[w][rr * 16 + (rr >> 1) + sl] =
        (col >= 1 && col <= MM)
            ? Rb[(size_t)(128 * q + 1 + rr) * (MM + 1) + col]
            : -BIGF;
  }
  __syncthreads();
  for (int G = 0; G < NGI; ++G) {
    const int a = G - OFS * w;
    if (a >= 0 && a < NA) {
      const int s0 = a * CW;
#pragma unroll
      for (int p = 0; p < CW; ++p) {
        const int j = 1087 - (s0 + p) - l;
        const bool act = (j >= 1) && (j <= MM);
        const bool vrt = (j < MM);
        float dnE = __shfl_down(a1e, 1);  // E(i2+1, j)
        float dnR = __shfl_down(a1r, 1);
        float dgE = __shfl_down(a2e, 1);  // E(i2+1, j+1)
        float dgR = __shfl_down(a2r, 1);
        const float rE = ringEl[wm1][j & 127];
        const float rR = ringRl[wm1][j & 127];
        if (L63) { dnE = rE; dnR = rR; dgE = rpE; dgR = rpR; }
        rpE = act ? rE : rpE;
        rpR = act ? rR : rpR;
        const float yjm = ylds[act ? (j - 1) : 0];
        const float rij2 = tl[16 + p];
        const float rij1 = tl[p];
        // i2 cell
        float d1 = xc - yjm; d1 *= d1;  // D(i2+1, j)
        float d2 = xb - yj;  d2 *= d2;  // D(i2, j+1) == D(i1+1, j+1)
        float d3 = xc - yj;  d3 *= d3;  // D(i2+1, j+1)
        const float t1 = vdn2 ? (dnR - rij2 - d1) : -BIGF;
        const float t2 = vrt ? (b1r - rij2 - d2) : -BIGF;
        const float t3 = (vdn2 && vrt) ? (dgR - rij2 - d3) : -BIGF;
        float e2 = dnE * __expf(t1) + b1e * __expf(t2) + dgE * __expf(t3);
        if (seedL && j == MM) e2 += 1.0f;
        // i1 cell (dn = fresh i2 values)
        float d4 = xb - yjm; d4 *= d4;  // D(i1+1, j)
        float d5 = xa - yj;  d5 *= d5;  // D(i1, j+1)
        const float u1 = rij2 - rij1 - d4;                  // always valid
        const float u2 = vrt ? (a1r - rij1 - d5) : -BIGF;
        const float u3 = vrt ? (b1r - rij1 - d2) : -BIGF;   // D(i1+1,j+1)==d2
        const float e1 = e2 * __expf(u1) + a1e * __expf(u2) + b1e * __expf(u3);
        tl[p] = e1;       // in-place E over R
        tl[16 + p] = e2;
        if (pub && act) { ringEl[w][j & 127] = e1; ringRl[w][j & 127] = rij1; }
        a2e = act ? a1e : a2e; a2r = act ? a1r : a2r;
        a1e = act ? e1 : a1e;  a1r = act ? rij1 : a1r;
        b1e = act ? e2 : b1e;  b1r = act ? rij2 : b1r;
        yj = yjm;
      }
      __builtin_amdgcn_wave_barrier();
      // coop: store E window a, then load R window a+1 into same slots
#pragma unroll
      for (int g = 0; g < 32; ++g) {
        const int rr = 4 * g + (l >> 4);
        const int sl = l & 15;
        const int col = 1087 - s0 - sl - (rr >> 1);
        const int ad = rr * 16 + (rr >> 1) + sl;
        const float v = tile[w][ad];
        if (col >= 1 && col <= MM)
          Eb[(size_t)(128 * q + rr) * MM + (col - 1)] = v;
        const int colN = col - CW;
        tile[w][ad] = (colN >= 1 && colN <= MM)
                          ? Rb[(size_t)(128 * q + 1 + rr) * (MM + 1) + colN]
                          : -BIGF;
      }
    }
    __syncthreads();
  }
}

extern "C" void kernel_launch(void* const* d_in, const int* in_sizes, int n_in,
                              void* d_out, int out_size, void* d_ws, size_t ws_size,
                              hipStream_t stream) {
  const float* x = (const float*)d_in[0];  // [16, 1024]
  const float* y = (const float*)d_in[1];  // [1024]
  float* out = (float*)d_out;
  float* score = out;                               // [16]
  float* D = out + NB;                              // [16,1024,1024]
  float* R = D + (size_t)NB * NN * MM;              // [16,1025,1025]
  float* E = R + (size_t)NB * (NN + 1) * (MM + 1);  // [16,1024,1024]

  hipLaunchKernelGGL(d_init_kernel, dim3((NB * NN * MM) / (256 * 4)), dim3(256), 0, stream,
                     x, y, D);
  hipLaunchKernelGGL(r_bound_kernel, dim3(NB), dim3(1024), 0, stream, R);
  hipLaunchKernelGGL(sdtw_fwd, dim3(NB), dim3(512), 0, stream, x, y, R, score);
  hipLaunchKernelGGL(sdtw_bwd, dim3(NB), dim3(512), 0, stream, x, y, R, E);
}